// Round 1
// baseline (1013.620 us; speedup 1.0000x reference)
//
#include <hip/hip_runtime.h>
#include <cstddef>

#define BATCH   2
#define SEQ     2048
#define DMODEL  1024
#define NH      16
#define HDIM    64
#define WIN     256
#define QKVLD   3072   // 3*DMODEL row stride of qkv
#define MTOT    4096   // BATCH*SEQ

// ---------------------------------------------------------------------------
// GEMM: C[M,N] = A[M,K] @ B[N,K]^T + bias[N]   (both row-major, K-contiguous)
// 128x128 block tile, Ktile=8, 256 threads, 8x8 micro-tile per thread.
// M,N,K must be multiples of 128/128/8 (they are: 4096/3072/1024).
// ---------------------------------------------------------------------------
__global__ __launch_bounds__(256)
void gemm_nt_kernel(const float* __restrict__ A, const float* __restrict__ Bm,
                    const float* __restrict__ bias, float* __restrict__ C,
                    int M, int N, int K) {
  __shared__ float As[8][132];   // [k][m], padded
  __shared__ float Bs[8][132];   // [k][n], padded
  const int t  = threadIdx.x;
  const int bm = blockIdx.y * 128;
  const int bn = blockIdx.x * 128;

  // loader: thread t loads one float4 of A and one of B per K-tile
  const int lr = t >> 1;          // row within 128-tile
  const int lk = (t & 1) * 4;     // k offset (0 or 4)
  const float* Ap = A  + (size_t)(bm + lr) * K + lk;
  const float* Bp = Bm + (size_t)(bn + lr) * K + lk;

  const int trow = (t >> 4) * 8;  // 16x16 thread grid, 8x8 micro
  const int tcol = (t & 15) * 8;

  float acc[8][8];
#pragma unroll
  for (int i = 0; i < 8; ++i)
#pragma unroll
    for (int j = 0; j < 8; ++j) acc[i][j] = 0.f;

  for (int k0 = 0; k0 < K; k0 += 8) {
    float4 av = *(const float4*)(Ap + k0);
    float4 bv = *(const float4*)(Bp + k0);
    __syncthreads();              // previous iteration's reads complete
    As[lk + 0][lr] = av.x; As[lk + 1][lr] = av.y;
    As[lk + 2][lr] = av.z; As[lk + 3][lr] = av.w;
    Bs[lk + 0][lr] = bv.x; Bs[lk + 1][lr] = bv.y;
    Bs[lk + 2][lr] = bv.z; Bs[lk + 3][lr] = bv.w;
    __syncthreads();
#pragma unroll
    for (int kk = 0; kk < 8; ++kk) {
      float a[8], b[8];
      *(float4*)(a)     = *(const float4*)&As[kk][trow];
      *(float4*)(a + 4) = *(const float4*)&As[kk][trow + 4];
      *(float4*)(b)     = *(const float4*)&Bs[kk][tcol];
      *(float4*)(b + 4) = *(const float4*)&Bs[kk][tcol + 4];
#pragma unroll
      for (int i = 0; i < 8; ++i)
#pragma unroll
        for (int j = 0; j < 8; ++j)
          acc[i][j] = fmaf(a[i], b[j], acc[i][j]);
    }
  }

#pragma unroll
  for (int i = 0; i < 8; ++i) {
    float* crow = C + (size_t)(bm + trow + i) * N + bn + tcol;
#pragma unroll
    for (int j = 0; j < 8; j += 4) {
      float4 o;
      o.x = acc[i][j + 0] + bias[bn + tcol + j + 0];
      o.y = acc[i][j + 1] + bias[bn + tcol + j + 1];
      o.z = acc[i][j + 2] + bias[bn + tcol + j + 2];
      o.w = acc[i][j + 3] + bias[bn + tcol + j + 3];
      *(float4*)(crow + j) = o;
    }
  }
}

// ---------------------------------------------------------------------------
// Flash attention, fp32. Allowed keys: j <= i + WIN (causal past + lookahead).
// One block = one (b,h) x 64-query tile. 256 threads, 16x16 grid, 4x4 micro.
// Streams 64-key tiles with online softmax (m,l per query row, shuffle-reduced
// across the 16 threads that share a row group).
// O written as [b, s, h, hd] = row-major [4096, 1024] (out-proj input layout).
// ---------------------------------------------------------------------------
__global__ __launch_bounds__(256)
void attn_kernel(const float* __restrict__ qkv, float* __restrict__ O) {
  const int t  = threadIdx.x;
  const int i0 = blockIdx.x * 64;          // query tile start
  const int bh = blockIdx.y;
  const int b  = bh >> 4;
  const int h  = bh & 15;
  const size_t base = (size_t)b * SEQ * QKVLD;
  const int hoff = h * HDIM;

  __shared__ float Qs[64][68];    // [d][q], scaled by 1/8
  __shared__ float KPs[64][68];   // K tile as [d][j]; reused as P tile [j][q]
  __shared__ float Vs[64][68];    // [j][d]

  // ---- load Q tile (transposed, scaled). 4 coalesced float4s per thread ----
  {
#pragma unroll
    for (int r = 0; r < 4; ++r) {
      const int row = r * 16 + (t >> 4);
      const int d   = (t & 15) * 4;
      float4 v = *(const float4*)(qkv + base + (size_t)(i0 + row) * QKVLD + hoff + d);
      Qs[d + 0][row] = v.x * 0.125f;
      Qs[d + 1][row] = v.y * 0.125f;
      Qs[d + 2][row] = v.z * 0.125f;
      Qs[d + 3][row] = v.w * 0.125f;
    }
  }

  const int trow = (t >> 4) * 4;  // local q rows
  const int tcol = (t & 15) * 4;  // local j / d cols

  float m_i[4], l_i[4], acc[4][4];
#pragma unroll
  for (int i = 0; i < 4; ++i) {
    m_i[i] = -1e30f; l_i[i] = 0.f;
#pragma unroll
    for (int j = 0; j < 4; ++j) acc[i][j] = 0.f;
  }

  const int nkt = min(i0 / 64 + 5, SEQ / 64);   // key tiles: j0 < min(i0+320, S)

  for (int kt = 0; kt < nkt; ++kt) {
    const int j0 = kt * 64;
    __syncthreads();   // prior PV reads of KPs/Vs done (and Q stores on iter 0)

    // ---- load K (transposed) and V tiles ----
#pragma unroll
    for (int r = 0; r < 4; ++r) {
      const int row = r * 16 + (t >> 4);
      const int d   = (t & 15) * 4;
      const float* src = qkv + base + (size_t)(j0 + row) * QKVLD + hoff + d;
      float4 kv = *(const float4*)(src + DMODEL);       // K slice
      float4 vv = *(const float4*)(src + 2 * DMODEL);   // V slice
      KPs[d + 0][row] = kv.x; KPs[d + 1][row] = kv.y;
      KPs[d + 2][row] = kv.z; KPs[d + 3][row] = kv.w;
      *(float4*)&Vs[row][d] = vv;
    }
    __syncthreads();

    // ---- S = (Q*scale) K^T, 4x4 micro ----
    float s[4][4];
#pragma unroll
    for (int i = 0; i < 4; ++i)
#pragma unroll
      for (int j = 0; j < 4; ++j) s[i][j] = 0.f;
    for (int d = 0; d < 64; ++d) {
      float4 a  = *(const float4*)&Qs[d][trow];
      float4 bv = *(const float4*)&KPs[d][tcol];
      const float av[4] = {a.x, a.y, a.z, a.w};
      const float bb[4] = {bv.x, bv.y, bv.z, bv.w};
#pragma unroll
      for (int i = 0; i < 4; ++i)
#pragma unroll
        for (int j = 0; j < 4; ++j)
          s[i][j] = fmaf(av[i], bb[j], s[i][j]);
    }

    // ---- mask: disallow j > i + WIN ----
#pragma unroll
    for (int i = 0; i < 4; ++i) {
      const int ig = i0 + trow + i;
#pragma unroll
      for (int j = 0; j < 4; ++j) {
        const int jg = j0 + tcol + j;
        if (jg > ig + WIN) s[i][j] = -1e30f;
      }
    }

    // ---- online softmax: row max across 16-lane group ----
    float m_new[4], alpha[4], rs[4];
#pragma unroll
    for (int i = 0; i < 4; ++i) {
      float v = fmaxf(fmaxf(s[i][0], s[i][1]), fmaxf(s[i][2], s[i][3]));
      v = fmaxf(v, __shfl_xor(v, 1));
      v = fmaxf(v, __shfl_xor(v, 2));
      v = fmaxf(v, __shfl_xor(v, 4));
      v = fmaxf(v, __shfl_xor(v, 8));
      m_new[i] = fmaxf(m_i[i], v);
      alpha[i] = __expf(m_i[i] - m_new[i]);
    }
#pragma unroll
    for (int i = 0; i < 4; ++i) {
      float r = 0.f;
#pragma unroll
      for (int j = 0; j < 4; ++j) {
        const float p = __expf(s[i][j] - m_new[i]);
        s[i][j] = p;
        r += p;
      }
      r += __shfl_xor(r, 1);
      r += __shfl_xor(r, 2);
      r += __shfl_xor(r, 4);
      r += __shfl_xor(r, 8);
      rs[i] = r;
    }
#pragma unroll
    for (int i = 0; i < 4; ++i) {
      l_i[i] = l_i[i] * alpha[i] + rs[i];
      m_i[i] = m_new[i];
#pragma unroll
      for (int j = 0; j < 4; ++j) acc[i][j] *= alpha[i];
    }

    __syncthreads();   // everyone done reading KPs as K

    // ---- write P transposed into KPs: P[j][q] ----
#pragma unroll
    for (int i = 0; i < 4; ++i)
#pragma unroll
      for (int j = 0; j < 4; ++j)
        KPs[tcol + j][trow + i] = s[i][j];
    __syncthreads();

    // ---- O += P V  (reduce over j) ----
    for (int jj = 0; jj < 64; ++jj) {
      float4 a  = *(const float4*)&KPs[jj][trow];
      float4 bv = *(const float4*)&Vs[jj][tcol];
      const float av[4] = {a.x, a.y, a.z, a.w};
      const float bb[4] = {bv.x, bv.y, bv.z, bv.w};
#pragma unroll
      for (int i = 0; i < 4; ++i)
#pragma unroll
        for (int j = 0; j < 4; ++j)
          acc[i][j] = fmaf(av[i], bb[j], acc[i][j]);
    }
  }

  // ---- epilogue: O[q][d] = acc/l, layout [b,s,h,hd] ----
  float* dst = O + (size_t)(b * SEQ + i0) * DMODEL + hoff;
#pragma unroll
  for (int i = 0; i < 4; ++i) {
    const float inv = 1.f / l_i[i];
    float4 o;
    o.x = acc[i][0] * inv; o.y = acc[i][1] * inv;
    o.z = acc[i][2] * inv; o.w = acc[i][3] * inv;
    *(float4*)(dst + (size_t)(trow + i) * DMODEL + tcol) = o;
  }
}

// ---------------------------------------------------------------------------
extern "C" void kernel_launch(void* const* d_in, const int* in_sizes, int n_in,
                              void* d_out, int out_size, void* d_ws, size_t ws_size,
                              hipStream_t stream) {
  const float* x   = (const float*)d_in[0];   // [2,2048,1024]
  const float* w1  = (const float*)d_in[1];   // [3072,1024]
  const float* b1  = (const float*)d_in[2];   // [3072]
  const float* w2  = (const float*)d_in[3];   // [1024,1024]
  const float* b2  = (const float*)d_in[4];   // [1024]
  float* out = (float*)d_out;                 // [2,2048,1024]

  float* qkv = (float*)d_ws;                        // [4096, 3072]
  float* Om  = qkv + (size_t)MTOT * QKVLD;          // [4096, 1024]

  // qkv = x @ in_proj_w^T + in_proj_b
  gemm_nt_kernel<<<dim3(QKVLD / 128, MTOT / 128), 256, 0, stream>>>(
      x, w1, b1, qkv, MTOT, QKVLD, DMODEL);

  // flash attention -> Om in [b,s,h,hd] layout
  attn_kernel<<<dim3(SEQ / 64, BATCH * NH), 256, 0, stream>>>(qkv, Om);

  // out = Om @ out_proj_w^T + out_proj_b
  gemm_nt_kernel<<<dim3(DMODEL / 128, MTOT / 128), 256, 0, stream>>>(
      Om, w2, b2, out, MTOT, DMODEL, DMODEL);
}

// Round 2
// 718.348 us; speedup vs baseline: 1.4110x; 1.4110x over previous
//
#include <hip/hip_runtime.h>
#include <cstddef>

#define BATCH   2
#define SEQ     2048
#define DMODEL  1024
#define NH      16
#define HDIM    64
#define WIN     256
#define QKVLD   3072   // 3*DMODEL row stride of qkv
#define MTOT    4096   // BATCH*SEQ

typedef __bf16 bf16;
typedef __attribute__((ext_vector_type(8)))  __bf16 bf16x8;
typedef __attribute__((ext_vector_type(16))) float  f32x16;

// ---------------------------------------------------------------------------
// Split-bf16 MFMA GEMM: C[M,N] = A[M,K] @ B[N,K]^T + bias[N]
// fp32 inputs decomposed on the fly: a = a_hi + a_lo (bf16 each);
// product via 3 MFMAs (hi*hi + hi*lo + lo*hi), residual error ~2^-18/operand.
// 128x128 tile, BK=32, 256 threads = 4 waves; wave w owns 32-row strip,
// 4 col-tiles of v_mfma_f32_32x32x16_bf16.
// A-frag: A[m=lane&31][k=(lane>>5)*8 + j]; B-frag: B[n=lane&31][k=...];
// C/D:    col=lane&31, row=(reg&3)+8*(reg>>2)+4*(lane>>5)   [m74/m101]
// ---------------------------------------------------------------------------
#define BKP 40   // bf16 row pad: 80B stride, 16B-aligned for b128 LDS ops

__global__ __launch_bounds__(256)
void gemm_nt_mfma(const float* __restrict__ A, const float* __restrict__ Bm,
                  const float* __restrict__ bias, float* __restrict__ C,
                  int M, int N, int K) {
  __shared__ __align__(16) bf16 Ah[128][BKP];
  __shared__ __align__(16) bf16 Al[128][BKP];
  __shared__ __align__(16) bf16 Bh[128][BKP];
  __shared__ __align__(16) bf16 Bl[128][BKP];

  const int t    = threadIdx.x;
  const int bm   = blockIdx.y * 128;
  const int bn   = blockIdx.x * 128;
  const int w    = t >> 6;          // wave id 0..3
  const int lane = t & 63;
  const int m    = lane & 31;       // MFMA row/col within 32-tile
  const int q    = lane >> 5;       // k-half select

  // staging: thread t loads 16 floats of A and 16 of B per K-stage
  const int lr = t >> 1;            // row 0..127
  const int lk = (t & 1) * 16;      // k offset 0 or 16
  const float* Ap = A  + (size_t)(bm + lr) * K + lk;
  const float* Bp = Bm + (size_t)(bn + lr) * K + lk;

  f32x16 acc[4];
#pragma unroll
  for (int c = 0; c < 4; ++c)
#pragma unroll
    for (int r = 0; r < 16; ++r) acc[c][r] = 0.f;

  for (int k0 = 0; k0 < K; k0 += 32) {
    float av[16], bv[16];
    *(float4*)(av + 0)  = *(const float4*)(Ap + k0 + 0);
    *(float4*)(av + 4)  = *(const float4*)(Ap + k0 + 4);
    *(float4*)(av + 8)  = *(const float4*)(Ap + k0 + 8);
    *(float4*)(av + 12) = *(const float4*)(Ap + k0 + 12);
    *(float4*)(bv + 0)  = *(const float4*)(Bp + k0 + 0);
    *(float4*)(bv + 4)  = *(const float4*)(Bp + k0 + 4);
    *(float4*)(bv + 8)  = *(const float4*)(Bp + k0 + 8);
    *(float4*)(bv + 12) = *(const float4*)(Bp + k0 + 12);

    __syncthreads();   // prior iteration's frag reads complete

    bf16x8 vh, vl;
#pragma unroll
    for (int half = 0; half < 2; ++half) {
#pragma unroll
      for (int u = 0; u < 8; ++u) {
        float x = av[half * 8 + u];
        bf16 h = (bf16)x;
        vh[u] = h;
        vl[u] = (bf16)(x - (float)h);
      }
      *(bf16x8*)&Ah[lr][lk + half * 8] = vh;
      *(bf16x8*)&Al[lr][lk + half * 8] = vl;
#pragma unroll
      for (int u = 0; u < 8; ++u) {
        float x = bv[half * 8 + u];
        bf16 h = (bf16)x;
        vh[u] = h;
        vl[u] = (bf16)(x - (float)h);
      }
      *(bf16x8*)&Bh[lr][lk + half * 8] = vh;
      *(bf16x8*)&Bl[lr][lk + half * 8] = vl;
    }
    __syncthreads();

#pragma unroll
    for (int ks = 0; ks < 2; ++ks) {
      const int kk = ks * 16 + q * 8;
      bf16x8 a_h = *(const bf16x8*)&Ah[w * 32 + m][kk];
      bf16x8 a_l = *(const bf16x8*)&Al[w * 32 + m][kk];
#pragma unroll
      for (int c = 0; c < 4; ++c) {
        bf16x8 b_h = *(const bf16x8*)&Bh[c * 32 + m][kk];
        bf16x8 b_l = *(const bf16x8*)&Bl[c * 32 + m][kk];
        acc[c] = __builtin_amdgcn_mfma_f32_32x32x16_bf16(a_h, b_h, acc[c], 0, 0, 0);
        acc[c] = __builtin_amdgcn_mfma_f32_32x32x16_bf16(a_h, b_l, acc[c], 0, 0, 0);
        acc[c] = __builtin_amdgcn_mfma_f32_32x32x16_bf16(a_l, b_h, acc[c], 0, 0, 0);
      }
    }
  }

  // epilogue: C/D layout col=lane&31(=m), row=(r&3)+8*(r>>2)+4*q
#pragma unroll
  for (int c = 0; c < 4; ++c) {
    const int col = bn + c * 32 + m;
    const float bb = bias[col];
#pragma unroll
    for (int r = 0; r < 16; ++r) {
      const int row = (r & 3) + 8 * (r >> 2) + 4 * q;
      C[(size_t)(bm + w * 32 + row) * N + col] = acc[c][r] + bb;
    }
  }
}

// ---------------------------------------------------------------------------
// Flash attention, fp32. Allowed keys: j <= i + WIN (causal past + lookahead).
// One block = one (b,h) x 64-query tile. 256 threads, 16x16 grid, 4x4 micro.
// P stored row-major [q][j] (float4 writes, 2-way banks = free) — fixes the
// 8-way conflict of the old transposed scalar write. PV reads P via per-row
// scalar broadcasts.
// O written as [b, s, h, hd] = row-major [4096, 1024].
// ---------------------------------------------------------------------------
__global__ __launch_bounds__(256)
void attn_kernel(const float* __restrict__ qkv, float* __restrict__ O) {
  const int t  = threadIdx.x;
  const int i0 = blockIdx.x * 64;          // query tile start
  const int bh = blockIdx.y;
  const int b  = bh >> 4;
  const int h  = bh & 15;
  const size_t base = (size_t)b * SEQ * QKVLD;
  const int hoff = h * HDIM;

  __shared__ float Qs[64][68];    // [d][q], scaled by 1/8
  __shared__ float KPs[64][68];   // K tile as [d][j]; reused as P tile [q][j]
  __shared__ float Vs[64][68];    // [j][d]

#pragma unroll
  for (int r = 0; r < 4; ++r) {
    const int row = r * 16 + (t >> 4);
    const int d   = (t & 15) * 4;
    float4 v = *(const float4*)(qkv + base + (size_t)(i0 + row) * QKVLD + hoff + d);
    Qs[d + 0][row] = v.x * 0.125f;
    Qs[d + 1][row] = v.y * 0.125f;
    Qs[d + 2][row] = v.z * 0.125f;
    Qs[d + 3][row] = v.w * 0.125f;
  }

  const int trow = (t >> 4) * 4;  // local q rows
  const int tcol = (t & 15) * 4;  // local j / d cols

  float m_i[4], l_i[4], acc[4][4];
#pragma unroll
  for (int i = 0; i < 4; ++i) {
    m_i[i] = -1e30f; l_i[i] = 0.f;
#pragma unroll
    for (int j = 0; j < 4; ++j) acc[i][j] = 0.f;
  }

  const int nkt = min(i0 / 64 + 5, SEQ / 64);   // key tiles: j0 < min(i0+320, S)

  for (int kt = 0; kt < nkt; ++kt) {
    const int j0 = kt * 64;
    __syncthreads();

#pragma unroll
    for (int r = 0; r < 4; ++r) {
      const int row = r * 16 + (t >> 4);
      const int d   = (t & 15) * 4;
      const float* src = qkv + base + (size_t)(j0 + row) * QKVLD + hoff + d;
      float4 kv = *(const float4*)(src + DMODEL);
      float4 vv = *(const float4*)(src + 2 * DMODEL);
      KPs[d + 0][row] = kv.x; KPs[d + 1][row] = kv.y;
      KPs[d + 2][row] = kv.z; KPs[d + 3][row] = kv.w;
      *(float4*)&Vs[row][d] = vv;
    }
    __syncthreads();

    // S = (Q*scale) K^T
    float s[4][4];
#pragma unroll
    for (int i = 0; i < 4; ++i)
#pragma unroll
      for (int j = 0; j < 4; ++j) s[i][j] = 0.f;
    for (int d = 0; d < 64; ++d) {
      float4 a  = *(const float4*)&Qs[d][trow];
      float4 bv = *(const float4*)&KPs[d][tcol];
      const float av[4] = {a.x, a.y, a.z, a.w};
      const float bb[4] = {bv.x, bv.y, bv.z, bv.w};
#pragma unroll
      for (int i = 0; i < 4; ++i)
#pragma unroll
        for (int j = 0; j < 4; ++j)
          s[i][j] = fmaf(av[i], bb[j], s[i][j]);
    }

    // mask: disallow j > i + WIN
#pragma unroll
    for (int i = 0; i < 4; ++i) {
      const int ig = i0 + trow + i;
#pragma unroll
      for (int j = 0; j < 4; ++j) {
        const int jg = j0 + tcol + j;
        if (jg > ig + WIN) s[i][j] = -1e30f;
      }
    }

    // online softmax (row groups of 16 lanes)
    float m_new[4], alpha[4], rs[4];
#pragma unroll
    for (int i = 0; i < 4; ++i) {
      float v = fmaxf(fmaxf(s[i][0], s[i][1]), fmaxf(s[i][2], s[i][3]));
      v = fmaxf(v, __shfl_xor(v, 1));
      v = fmaxf(v, __shfl_xor(v, 2));
      v = fmaxf(v, __shfl_xor(v, 4));
      v = fmaxf(v, __shfl_xor(v, 8));
      m_new[i] = fmaxf(m_i[i], v);
      alpha[i] = __expf(m_i[i] - m_new[i]);
    }
#pragma unroll
    for (int i = 0; i < 4; ++i) {
      float r = 0.f;
#pragma unroll
      for (int j = 0; j < 4; ++j) {
        const float p = __expf(s[i][j] - m_new[i]);
        s[i][j] = p;
        r += p;
      }
      r += __shfl_xor(r, 1);
      r += __shfl_xor(r, 2);
      r += __shfl_xor(r, 4);
      r += __shfl_xor(r, 8);
      rs[i] = r;
    }
#pragma unroll
    for (int i = 0; i < 4; ++i) {
      l_i[i] = l_i[i] * alpha[i] + rs[i];
      m_i[i] = m_new[i];
#pragma unroll
      for (int j = 0; j < 4; ++j) acc[i][j] *= alpha[i];
    }

    __syncthreads();   // everyone done reading KPs as K

    // write P row-major: KPs[q][j], float4 per row (2-way banks, free)
#pragma unroll
    for (int i = 0; i < 4; ++i) {
      float4 pr;
      pr.x = s[i][0]; pr.y = s[i][1]; pr.z = s[i][2]; pr.w = s[i][3];
      *(float4*)&KPs[trow + i][tcol] = pr;
    }
    __syncthreads();

    // O += P V : P rows broadcast-read across the 16-lane row group
    for (int jj = 0; jj < 64; ++jj) {
      float4 bv = *(const float4*)&Vs[jj][tcol];
      const float bb[4] = {bv.x, bv.y, bv.z, bv.w};
      const float p0 = KPs[trow + 0][jj];
      const float p1 = KPs[trow + 1][jj];
      const float p2 = KPs[trow + 2][jj];
      const float p3 = KPs[trow + 3][jj];
#pragma unroll
      for (int j = 0; j < 4; ++j) {
        acc[0][j] = fmaf(p0, bb[j], acc[0][j]);
        acc[1][j] = fmaf(p1, bb[j], acc[1][j]);
        acc[2][j] = fmaf(p2, bb[j], acc[2][j]);
        acc[3][j] = fmaf(p3, bb[j], acc[3][j]);
      }
    }
  }

  // epilogue
  float* dst = O + (size_t)(b * SEQ + i0) * DMODEL + hoff;
#pragma unroll
  for (int i = 0; i < 4; ++i) {
    const float inv = 1.f / l_i[i];
    float4 o;
    o.x = acc[i][0] * inv; o.y = acc[i][1] * inv;
    o.z = acc[i][2] * inv; o.w = acc[i][3] * inv;
    *(float4*)(dst + (size_t)(trow + i) * DMODEL + tcol) = o;
  }
}

// ---------------------------------------------------------------------------
extern "C" void kernel_launch(void* const* d_in, const int* in_sizes, int n_in,
                              void* d_out, int out_size, void* d_ws, size_t ws_size,
                              hipStream_t stream) {
  const float* x   = (const float*)d_in[0];   // [2,2048,1024]
  const float* w1  = (const float*)d_in[1];   // [3072,1024]
  const float* b1  = (const float*)d_in[2];   // [3072]
  const float* w2  = (const float*)d_in[3];   // [1024,1024]
  const float* b2  = (const float*)d_in[4];   // [1024]
  float* out = (float*)d_out;                 // [2,2048,1024]

  float* qkv = (float*)d_ws;                        // [4096, 3072]
  float* Om  = qkv + (size_t)MTOT * QKVLD;          // [4096, 1024]

  gemm_nt_mfma<<<dim3(QKVLD / 128, MTOT / 128), 256, 0, stream>>>(
      x, w1, b1, qkv, MTOT, QKVLD, DMODEL);

  attn_kernel<<<dim3(SEQ / 64, BATCH * NH), 256, 0, stream>>>(qkv, Om);

  gemm_nt_mfma<<<dim3(DMODEL / 128, MTOT / 128), 256, 0, stream>>>(
      Om, w2, b2, out, MTOT, DMODEL, DMODEL);
}

// Round 3
// 347.367 us; speedup vs baseline: 2.9180x; 2.0680x over previous
//
#include <hip/hip_runtime.h>
#include <cstddef>

#define BATCH   2
#define SEQ     2048
#define DMODEL  1024
#define NH      16
#define HDIM    64
#define WIN     256
#define QKVLD   3072
#define QKVLLD  2048   // qkv-lo stores only Q+K columns (0..2047)
#define MTOT    4096

typedef __bf16 bf16;
typedef __attribute__((ext_vector_type(8)))  __bf16 bf16x8;
typedef __attribute__((ext_vector_type(4)))  float  f32x4;
typedef __attribute__((ext_vector_type(16))) float  f32x16;

#define GLOAD_LDS(gp, lp) __builtin_amdgcn_global_load_lds( \
    (const __attribute__((address_space(1))) void*)(gp),    \
    (__attribute__((address_space(3))) void*)(lp), 16, 0, 0)

// ---------------------------------------------------------------------------
// Pre-pass: split fp32 array into bf16 hi + lo arrays (v = hi + lo).
// ---------------------------------------------------------------------------
__global__ __launch_bounds__(256)
void cvt_split(const float* __restrict__ src, bf16* __restrict__ h,
               bf16* __restrict__ l, int n) {
  const int i = (blockIdx.x * 256 + threadIdx.x) * 8;
  if (i >= n) return;
  float4 a = *(const float4*)(src + i);
  float4 b = *(const float4*)(src + i + 4);
  const float f[8] = {a.x, a.y, a.z, a.w, b.x, b.y, b.z, b.w};
  bf16x8 vh, vl;
#pragma unroll
  for (int j = 0; j < 8; ++j) {
    bf16 hh = (bf16)f[j];
    vh[j] = hh;
    vl[j] = (bf16)(f[j] - (float)hh);
  }
  *(bf16x8*)(h + i) = vh;
  *(bf16x8*)(l + i) = vl;
}

// ---------------------------------------------------------------------------
// Split-bf16 MFMA GEMM, m97 structure. C = (Ah+Al)(Bh+Bl)^T + bias.
// A,B pre-split bf16 [rows][K]. 128x128 tile, BK=32, 256 thr / 4 waves,
// wave tile 64x64 = 4x4 of v_mfma_f32_16x16x32_bf16, 3 MFMAs per (hi/lo).
// Staging: pure global_load_lds dwordx4 (8 insts/wave/stage, no VALU).
// Output: fp32 (Cf) or split bf16 (Ch full ld N, Cl ld locols, cols<locols).
// ---------------------------------------------------------------------------
__global__ __launch_bounds__(256)
void gemm_split(const bf16* __restrict__ Ah, const bf16* __restrict__ Al,
                const bf16* __restrict__ Bh, const bf16* __restrict__ Bl,
                const float* __restrict__ bias, int K, int N,
                float* __restrict__ Cf, bf16* __restrict__ Ch,
                bf16* __restrict__ Cl, int locols) {
  __shared__ bf16 sAh[128 * 32];
  __shared__ bf16 sAl[128 * 32];
  __shared__ bf16 sBh[128 * 32];
  __shared__ bf16 sBl[128 * 32];

  const int t = threadIdx.x, w = t >> 6, lane = t & 63;
  const int ln15 = lane & 15, quad = lane >> 4;
  const int bm = blockIdx.y * 128, bn = blockIdx.x * 128;
  const int wrow = (w & 1) * 64, wcol = (w >> 1) * 64;

  // DMA element offsets: lane deposits at ldsbase + lane*16B.
  // lane -> row += lane>>2, kcol = (lane&3)*8  (rows are 32 bf16 = 64B)
  const int drow = lane >> 2;
  const int dkcol = (lane & 3) * 8;

  f32x4 acc[4][4];
#pragma unroll
  for (int i = 0; i < 4; ++i)
#pragma unroll
    for (int j = 0; j < 4; ++j)
#pragma unroll
      for (int r = 0; r < 4; ++r) acc[i][j][r] = 0.f;

  for (int k0 = 0; k0 < K; k0 += 32) {
    __syncthreads();   // previous stage frag reads complete
#pragma unroll
    for (int half = 0; half < 2; ++half) {
      const int r = w * 32 + half * 16 + drow;
      const size_t goffA = (size_t)(bm + r) * K + k0 + dkcol;
      const size_t goffB = (size_t)(bn + r) * K + k0 + dkcol;
      const int loff = (w * 32 + half * 16) * 32;
      GLOAD_LDS(Ah + goffA, sAh + loff);
      GLOAD_LDS(Al + goffA, sAl + loff);
      GLOAD_LDS(Bh + goffB, sBh + loff);
      GLOAD_LDS(Bl + goffB, sBl + loff);
    }
    __syncthreads();

    bf16x8 afh[4], afl[4], bfh[4], bfl[4];
#pragma unroll
    for (int mt = 0; mt < 4; ++mt) {
      const int off = (wrow + mt * 16 + ln15) * 32 + quad * 8;
      afh[mt] = *(const bf16x8*)&sAh[off];
      afl[mt] = *(const bf16x8*)&sAl[off];
    }
#pragma unroll
    for (int nt = 0; nt < 4; ++nt) {
      const int off = (wcol + nt * 16 + ln15) * 32 + quad * 8;
      bfh[nt] = *(const bf16x8*)&sBh[off];
      bfl[nt] = *(const bf16x8*)&sBl[off];
    }
#pragma unroll
    for (int mt = 0; mt < 4; ++mt)
#pragma unroll
      for (int nt = 0; nt < 4; ++nt) {
        acc[mt][nt] = __builtin_amdgcn_mfma_f32_16x16x32_bf16(afh[mt], bfh[nt], acc[mt][nt], 0, 0, 0);
        acc[mt][nt] = __builtin_amdgcn_mfma_f32_16x16x32_bf16(afh[mt], bfl[nt], acc[mt][nt], 0, 0, 0);
        acc[mt][nt] = __builtin_amdgcn_mfma_f32_16x16x32_bf16(afl[mt], bfh[nt], acc[mt][nt], 0, 0, 0);
      }
  }

  // epilogue: C/D layout col=lane&15, row=quad*4+reg
  float bb[4];
#pragma unroll
  for (int nt = 0; nt < 4; ++nt) bb[nt] = bias ? bias[bn + wcol + nt * 16 + ln15] : 0.f;

#pragma unroll
  for (int mt = 0; mt < 4; ++mt)
#pragma unroll
    for (int r = 0; r < 4; ++r) {
      const size_t grow = (size_t)(bm + wrow + mt * 16 + quad * 4 + r);
#pragma unroll
      for (int nt = 0; nt < 4; ++nt) {
        const int col = bn + wcol + nt * 16 + ln15;
        const float v = acc[mt][nt][r] + bb[nt];
        if (Cf) {
          Cf[grow * N + col] = v;
        } else {
          const bf16 hh = (bf16)v;
          Ch[grow * N + col] = hh;
          if (col < locols) Cl[grow * locols + col] = (bf16)(v - (float)hh);
        }
      }
    }
}

// ---------------------------------------------------------------------------
// MFMA flash attention (bf16). Allowed keys: j <= i + WIN.
// Block = (b,h) x 128-query tile; 4 waves, wave = 32 q-rows; K-tiles of 64.
// Split-bf16 QK^T (Q,K hi/lo -> 3 MFMAs); no-max softmax: p = exp2(s*log2e/8)
// (scores O(10), safe in fp32, clamped at 60); row-sum l via a ones-column
// MFMA accumulated alongside O. P -> LDS [row][72] -> A-frags for PV.
// K staged via frag-ordered global_load_lds (async, zero VALU); V hi-only,
// scatter-transposed into frag order.
// ---------------------------------------------------------------------------
__global__ __launch_bounds__(256)
void attn_mfma(const bf16* __restrict__ qkvh, const bf16* __restrict__ qkvl,
               bf16* __restrict__ Omh, bf16* __restrict__ Oml) {
  const int t = threadIdx.x, w = t >> 6, lane = t & 63;
  const int ln31 = lane & 31, half = lane >> 5;
  const int qt = blockIdx.x, i0 = qt * 128;
  const int bh = blockIdx.y, b = bh >> 4, h = bh & 15;
  const int colQ = h * 64, colK = DMODEL + h * 64, colV = 2 * DMODEL + h * 64;

  __shared__ bf16 sKh[8 * 64 * 8];   // frag slot ((c*4+ks)*64+lane)*8
  __shared__ bf16 sKl[8 * 64 * 8];
  __shared__ bf16 sVt[8 * 64 * 8];   // ((cn*4+ks)*64+lane)*8 : V^T frags
  __shared__ bf16 sP[128 * 72];      // P row-major, ld 72

  // ---- Q fragments (loaded once; scale log2(e)/8 folded in; re-split) ----
  bf16x8 qh[4], ql[4];
  {
    const size_t rowQ = (size_t)(b * SEQ + i0 + w * 32 + ln31);
#pragma unroll
    for (int ks = 0; ks < 4; ++ks) {
      bf16x8 vh = *(const bf16x8*)(qkvh + rowQ * QKVLD + colQ + ks * 16 + half * 8);
      bf16x8 vl = *(const bf16x8*)(qkvl + rowQ * QKVLLD + colQ + ks * 16 + half * 8);
#pragma unroll
      for (int j = 0; j < 8; ++j) {
        float f = ((float)vh[j] + (float)vl[j]) * 0.1803368801111204f;  // log2(e)/8
        bf16 hh = (bf16)f;
        qh[ks][j] = hh;
        ql[ks][j] = (bf16)(f - (float)hh);
      }
    }
  }
  bf16x8 onesf;
#pragma unroll
  for (int j = 0; j < 8; ++j) onesf[j] = (ln31 == 0) ? (bf16)1.0f : (bf16)0.0f;

  f32x16 accO0, accO1, accL;
#pragma unroll
  for (int r = 0; r < 16; ++r) { accO0[r] = 0.f; accO1[r] = 0.f; accL[r] = 0.f; }

  const int vkey = t >> 2, vdb = (t & 3) * 16;   // V staging mapping
  const int nkt = min(2 * qt + 6, SEQ / 64);

  for (int kt = 0; kt < nkt; ++kt) {
    const int j0 = kt * 64;
    __syncthreads();   // previous tile's frag reads complete

    // ---- K staging: 16 frag-ordered global_load_lds, 4 per wave ----
#pragma unroll
    for (int ii = 0; ii < 4; ++ii) {
      const int s = w * 4 + ii;            // 0..15
      const int cs = s & 7, c = cs >> 2, ks = cs & 3;
      const int n = c * 32 + ln31;
      const int kk = ks * 16 + half * 8;
      const size_t gr = (size_t)(b * SEQ + j0 + n);
      if (s < 8) {
        GLOAD_LDS(qkvh + gr * QKVLD + colK + kk, sKh + cs * 512);
      } else {
        GLOAD_LDS(qkvl + gr * QKVLLD + colK + kk, sKl + cs * 512);
      }
    }
    // ---- V staging: hi only, scatter-transpose into frag order ----
    {
      const size_t gr = (size_t)(b * SEQ + j0 + vkey);
      bf16x8 v0 = *(const bf16x8*)(qkvh + gr * QKVLD + colV + vdb);
      bf16x8 v1 = *(const bf16x8*)(qkvh + gr * QKVLD + colV + vdb + 8);
      const int ks2 = vkey >> 4, qp = (vkey >> 3) & 1, jj = vkey & 7;
#pragma unroll
      for (int e = 0; e < 16; ++e) {
        const int d = vdb + e;
        const int cn = d >> 5;
        sVt[((cn * 4 + ks2) * 64 + (d & 31) + 32 * qp) * 8 + jj] =
            (e < 8) ? v0[e] : v1[e - 8];
      }
    }
    __syncthreads();   // drains vmcnt (DMA) + LDS writes

    // wave-uniform skip: this wave's rows all mask out this key tile
    if (j0 <= i0 + w * 32 + 31 + WIN) {
      // ---- S = Q K^T (split: hh + hl + lh) ----
      f32x16 S0, S1;
#pragma unroll
      for (int r = 0; r < 16; ++r) { S0[r] = 0.f; S1[r] = 0.f; }
#pragma unroll
      for (int ks = 0; ks < 4; ++ks) {
        bf16x8 kh0 = *(const bf16x8*)&sKh[((0 * 4 + ks) * 64 + lane) * 8];
        bf16x8 kl0 = *(const bf16x8*)&sKl[((0 * 4 + ks) * 64 + lane) * 8];
        bf16x8 kh1 = *(const bf16x8*)&sKh[((1 * 4 + ks) * 64 + lane) * 8];
        bf16x8 kl1 = *(const bf16x8*)&sKl[((1 * 4 + ks) * 64 + lane) * 8];
        S0 = __builtin_amdgcn_mfma_f32_32x32x16_bf16(qh[ks], kh0, S0, 0, 0, 0);
        S0 = __builtin_amdgcn_mfma_f32_32x32x16_bf16(qh[ks], kl0, S0, 0, 0, 0);
        S0 = __builtin_amdgcn_mfma_f32_32x32x16_bf16(ql[ks], kh0, S0, 0, 0, 0);
        S1 = __builtin_amdgcn_mfma_f32_32x32x16_bf16(qh[ks], kh1, S1, 0, 0, 0);
        S1 = __builtin_amdgcn_mfma_f32_32x32x16_bf16(qh[ks], kl1, S1, 0, 0, 0);
        S1 = __builtin_amdgcn_mfma_f32_32x32x16_bf16(ql[ks], kh1, S1, 0, 0, 0);
      }

      // ---- mask, exp2, write P (bf16) to LDS row-major ----
#pragma unroll
      for (int c = 0; c < 2; ++c) {
        f32x16& S = c ? S1 : S0;
        const int jg = j0 + c * 32 + ln31;
        const bool may = (j0 + c * 32 + 31) > (i0 + w * 32 + WIN);
#pragma unroll
        for (int r = 0; r < 16; ++r) {
          const int rl = (r & 3) + 8 * (r >> 2) + 4 * half;
          float sv = S[r];
          if (may && (jg > i0 + w * 32 + rl + WIN)) sv = -1e30f;
          sv = exp2f(fminf(sv, 60.f));
          sP[(w * 32 + rl) * 72 + c * 32 + ln31] = (bf16)sv;
        }
      }

      // ---- O += P V ; l += P 1  (wave-local P, no barrier needed) ----
#pragma unroll
      for (int ks = 0; ks < 4; ++ks) {
        bf16x8 pA  = *(const bf16x8*)&sP[(w * 32 + ln31) * 72 + ks * 16 + half * 8];
        bf16x8 vB0 = *(const bf16x8*)&sVt[((0 * 4 + ks) * 64 + lane) * 8];
        bf16x8 vB1 = *(const bf16x8*)&sVt[((1 * 4 + ks) * 64 + lane) * 8];
        accO0 = __builtin_amdgcn_mfma_f32_32x32x16_bf16(pA, vB0, accO0, 0, 0, 0);
        accO1 = __builtin_amdgcn_mfma_f32_32x32x16_bf16(pA, vB1, accO1, 0, 0, 0);
        accL  = __builtin_amdgcn_mfma_f32_32x32x16_bf16(pA, onesf, accL, 0, 0, 0);
      }
    }
  }

  // ---- epilogue: O /= l, write Om hi/lo ([b*S+i, h*64+d], ld 1024) ----
#pragma unroll
  for (int r = 0; r < 16; ++r) {
    const int rl = (r & 3) + 8 * (r >> 2) + 4 * half;
    const float lv = __shfl(accL[r], lane & 32, 64);   // col-0 lane of my half
    const float inv = 1.0f / lv;
    const size_t grow = (size_t)(b * SEQ + i0 + w * 32 + rl);
    const int col0 = h * 64 + ln31;
    const float v0 = accO0[r] * inv;
    const float v1 = accO1[r] * inv;
    const bf16 h0 = (bf16)v0, h1 = (bf16)v1;
    Omh[grow * DMODEL + col0]      = h0;
    Oml[grow * DMODEL + col0]      = (bf16)(v0 - (float)h0);
    Omh[grow * DMODEL + col0 + 32] = h1;
    Oml[grow * DMODEL + col0 + 32] = (bf16)(v1 - (float)h1);
  }
}

// ---------------------------------------------------------------------------
extern "C" void kernel_launch(void* const* d_in, const int* in_sizes, int n_in,
                              void* d_out, int out_size, void* d_ws, size_t ws_size,
                              hipStream_t stream) {
  const float* x  = (const float*)d_in[0];
  const float* w1 = (const float*)d_in[1];
  const float* b1 = (const float*)d_in[2];
  const float* w2 = (const float*)d_in[3];
  const float* b2 = (const float*)d_in[4];
  float* out = (float*)d_out;

  char* ws = (char*)d_ws;
  bf16* qkvh = (bf16*)(ws + 0);                    // [4096][3072]
  bf16* qkvl = (bf16*)(ws + 25165824);             // [4096][2048] (Q,K cols)
  bf16* xh   = (bf16*)(ws + 41943040);             // [4096][1024]
  bf16* xl   = (bf16*)(ws + 50331648);
  bf16* w1h  = (bf16*)(ws + 58720256);             // [3072][1024]
  bf16* w1l  = (bf16*)(ws + 65011712);
  bf16* w2h  = (bf16*)(ws + 71303168);             // [1024][1024]
  bf16* w2l  = (bf16*)(ws + 73400320);
  bf16* Omh  = (bf16*)(ws + 41943040);             // reuse xh (dead after gemm1)
  bf16* Oml  = (bf16*)(ws + 50331648);             // reuse xl

  cvt_split<<<dim3(MTOT * DMODEL / 2048), 256, 0, stream>>>(x,  xh,  xl,  MTOT * DMODEL);
  cvt_split<<<dim3(3 * DMODEL * DMODEL / 2048), 256, 0, stream>>>(w1, w1h, w1l, 3 * DMODEL * DMODEL);
  cvt_split<<<dim3(DMODEL * DMODEL / 2048), 256, 0, stream>>>(w2, w2h, w2l, DMODEL * DMODEL);

  // qkv = x @ w1^T + b1  -> split bf16 (lo only for Q,K cols)
  gemm_split<<<dim3(QKVLD / 128, MTOT / 128), 256, 0, stream>>>(
      xh, xl, w1h, w1l, b1, DMODEL, QKVLD, nullptr, qkvh, qkvl, QKVLLD);

  attn_mfma<<<dim3(SEQ / 128, BATCH * NH), 256, 0, stream>>>(qkvh, qkvl, Omh, Oml);

  // out = Om @ w2^T + b2 (fp32 out)
  gemm_split<<<dim3(DMODEL / 128, MTOT / 128), 256, 0, stream>>>(
      Omh, Oml, w2h, w2l, b2, DMODEL, DMODEL, out, nullptr, nullptr, 0);
}